// Round 33
// baseline (28.791 us; speedup 1.0000x reference)
//
#include <hip/hip_runtime.h>
#include <cstdint>
#include <cstddef>

#define NCOL 12288    // N
#define KHALF 2048    // K/2 packed rows; K=4096, 32 groups of 64 kh-rows
#define NGRP 32
#define COLT 256      // columns per block

// round-to-nearest-even f32 -> bf16 value, returned as f32 (fallback path only)
__device__ __forceinline__ float bf16_rne(float f) {
    uint32_t u; __builtin_memcpy(&u, &f, 4);
    u = (u + 0x7FFFu + ((u >> 16) & 1u)) & 0xFFFF0000u;
    float r; __builtin_memcpy(&r, &u, 4);
    return r;
}

// ---------------------------------------------------------------------------
// Fused split-K GEMV. Block = 256 threads = 4 waves; covers COLT=256 cols x
// one full dequant group (64 kh-rows); wave w owns rows [16w,16w+16).
// 4-way LDS reduce, then wave 0 atomicAdds the group-partial into out[]
// (f32 global atomics are device-scope -> cross-XCD coherent).
// Grid (48, 32) = 1536 blocks. out[] must be pre-zeroed (memset in-graph).
// ---------------------------------------------------------------------------
__global__ __launch_bounds__(256) void gemv_fused(
    const float* __restrict__ x,       // f32[4096]
    const uint32_t* __restrict__ wq,   // [KHALF][NCOL]
    const float* __restrict__ sc,      // [32][NCOL]
    const float* __restrict__ zr,      // [32][NCOL]
    float* __restrict__ out)           // f32[NCOL], pre-zeroed
{
    const int tx   = threadIdx.x;
    const int lane = tx & 63;
    const int wave = tx >> 6;                    // 0..3
    const int g    = blockIdx.y;                 // dequant group
    const int kh0  = g * 64 + wave * 16;
    const int n0   = blockIdx.x * COLT + lane * 4;

    const float4 s4 = *(const float4*)(sc + (size_t)g * NCOL + n0);
    const float4 z4 = *(const float4*)(zr + (size_t)g * NCOL + n0);

    float a0 = 0.f, a1 = 0.f, a2 = 0.f, a3 = 0.f;
    const uint4* wp = (const uint4*)(wq + (size_t)kh0 * NCOL + n0);

    #pragma unroll
    for (int r = 0; r < 16; ++r) {
        const uint4 v = wp[(size_t)r * (NCOL / 4)];
        const float xl = x[2 * (kh0 + r)];       // uniform -> scalar load
        const float xh = x[2 * (kh0 + r) + 1];
        a0 = fmaf(xl, bf16_rne(((float)(v.x & 15u)        - z4.x) * s4.x), a0);
        a0 = fmaf(xh, bf16_rne(((float)((v.x >> 4) & 15u) - z4.x) * s4.x), a0);
        a1 = fmaf(xl, bf16_rne(((float)(v.y & 15u)        - z4.y) * s4.y), a1);
        a1 = fmaf(xh, bf16_rne(((float)((v.y >> 4) & 15u) - z4.y) * s4.y), a1);
        a2 = fmaf(xl, bf16_rne(((float)(v.z & 15u)        - z4.z) * s4.z), a2);
        a2 = fmaf(xh, bf16_rne(((float)((v.z >> 4) & 15u) - z4.z) * s4.z), a2);
        a3 = fmaf(xl, bf16_rne(((float)(v.w & 15u)        - z4.w) * s4.w), a3);
        a3 = fmaf(xh, bf16_rne(((float)((v.w >> 4) & 15u) - z4.w) * s4.w), a3);
    }

    __shared__ float red[4][COLT];               // 4 KB
    red[wave][lane * 4 + 0] = a0;
    red[wave][lane * 4 + 1] = a1;
    red[wave][lane * 4 + 2] = a2;
    red[wave][lane * 4 + 3] = a3;
    __syncthreads();

    if (wave == 0) {
        const int c = lane * 4;
        const float sx = (red[0][c + 0] + red[1][c + 0]) + (red[2][c + 0] + red[3][c + 0]);
        const float sy = (red[0][c + 1] + red[1][c + 1]) + (red[2][c + 1] + red[3][c + 1]);
        const float sz = (red[0][c + 2] + red[1][c + 2]) + (red[2][c + 2] + red[3][c + 2]);
        const float sw = (red[0][c + 3] + red[1][c + 3]) + (red[2][c + 3] + red[3][c + 3]);
        atomicAdd(out + n0 + 0, sx);
        atomicAdd(out + n0 + 1, sy);
        atomicAdd(out + n0 + 2, sz);
        atomicAdd(out + n0 + 3, sw);
    }
}

// Fallback (should never trigger): 1 thread per column, full K, exact bf16 out.
__global__ void gemv_simple(
    const float* __restrict__ x, const uint32_t* __restrict__ wq,
    const float* __restrict__ sc, const float* __restrict__ zr,
    float* __restrict__ out)
{
    const int n = blockIdx.x * blockDim.x + threadIdx.x;
    if (n >= NCOL) return;
    float acc = 0.f;
    for (int g = 0; g < NGRP; ++g) {
        const float s = sc[(size_t)g * NCOL + n];
        const float z = zr[(size_t)g * NCOL + n];
        #pragma unroll 8
        for (int r = 0; r < 64; ++r) {
            const int kh = g * 64 + r;
            const uint32_t e = wq[(size_t)kh * NCOL + n];
            acc = fmaf(x[2 * kh],     bf16_rne(((float)(e & 15u)        - z) * s), acc);
            acc = fmaf(x[2 * kh + 1], bf16_rne(((float)((e >> 4) & 15u) - z) * s), acc);
        }
    }
    out[n] = bf16_rne(acc);
}

extern "C" void kernel_launch(void* const* d_in, const int* in_sizes, int n_in,
                              void* d_out, int out_size, void* d_ws, size_t ws_size,
                              hipStream_t stream) {
    (void)in_sizes; (void)n_in; (void)out_size; (void)d_ws; (void)ws_size;
    const float*    x  = (const float*)d_in[0];   // f32 upcast of bf16
    const uint32_t* wq = (const uint32_t*)d_in[1];
    const float*    sc = (const float*)d_in[2];
    const float*    zr = (const float*)d_in[3];
    float* out = (float*)d_out;                   // output dtype is FLOAT32

    // Zero the accumulator each call (captured into the graph, so every
    // replay re-zeros; harness does NOT re-zero between replays).
    hipError_t me = hipMemsetAsync(d_out, 0, (size_t)NCOL * 4, stream);
    if (me == hipSuccess) {
        gemv_fused<<<dim3(NCOL / COLT, NGRP), dim3(256), 0, stream>>>(x, wq, sc, zr, out);
    } else {
        gemv_simple<<<dim3(NCOL / 64), dim3(64), 0, stream>>>(x, wq, sc, zr, out);
    }
}

// Round 34
// 24.672 us; speedup vs baseline: 1.1669x; 1.1669x over previous
//
#include <hip/hip_runtime.h>
#include <hip/hip_bf16.h>
#include <cstdint>
#include <cstddef>

#define NCOL 12288    // N
#define KHALF 2048    // K/2 packed rows; K=4096, 32 groups of 64 kh-rows
#define NGRP 32
#define COLT 256      // columns per block

// exact reference semantics: RNE round to bf16, back to f32 (compiler emits
// v_cvt_pk_bf16_f32 for adjacent pairs on gfx950)
__device__ __forceinline__ float bf16r(float f) {
    return __bfloat162float(__float2bfloat16(f));
}

// ---------------------------------------------------------------------------
// Split-K partial GEMV. Block = 256 threads = 4 waves; covers COLT=256 cols x
// one full dequant group (64 kh-rows); wave w owns rows [16w,16w+16).
// 4-way LDS reduce; wave 0 writes group-partial to ws[g][n].
// Grid (48, 32) = 1536 blocks -> 6 blocks/CU, 24 waves/CU.
// Scales/zeros read exactly once per group; x loads wave-uniform (scalar).
// ---------------------------------------------------------------------------
__global__ __launch_bounds__(256) void gemv_part(
    const float* __restrict__ x,       // f32[4096]
    const uint32_t* __restrict__ wq,   // [KHALF][NCOL]
    const float* __restrict__ sc,      // [32][NCOL]
    const float* __restrict__ zr,      // [32][NCOL]
    float* __restrict__ ws)            // [NGRP][NCOL]
{
    const int tx   = threadIdx.x;
    const int lane = tx & 63;
    const int wave = tx >> 6;                    // 0..3
    const int g    = blockIdx.y;                 // dequant group
    const int kh0  = g * 64 + wave * 16;
    const int n0   = blockIdx.x * COLT + lane * 4;

    const float4 s4 = *(const float4*)(sc + (size_t)g * NCOL + n0);
    const float4 z4 = *(const float4*)(zr + (size_t)g * NCOL + n0);

    float a0 = 0.f, a1 = 0.f, a2 = 0.f, a3 = 0.f;
    const uint4* wp = (const uint4*)(wq + (size_t)kh0 * NCOL + n0);

    #pragma unroll
    for (int r = 0; r < 16; ++r) {
        const uint4 v = wp[(size_t)r * (NCOL / 4)];
        const float xl = x[2 * (kh0 + r)];       // uniform -> scalar load
        const float xh = x[2 * (kh0 + r) + 1];
        // dequant pairs (lo,hi) per column; adjacent casts fuse to cvt_pk
        const float d0l = bf16r(((float)(v.x & 15u)        - z4.x) * s4.x);
        const float d0h = bf16r(((float)((v.x >> 4) & 15u) - z4.x) * s4.x);
        const float d1l = bf16r(((float)(v.y & 15u)        - z4.y) * s4.y);
        const float d1h = bf16r(((float)((v.y >> 4) & 15u) - z4.y) * s4.y);
        const float d2l = bf16r(((float)(v.z & 15u)        - z4.z) * s4.z);
        const float d2h = bf16r(((float)((v.z >> 4) & 15u) - z4.z) * s4.z);
        const float d3l = bf16r(((float)(v.w & 15u)        - z4.w) * s4.w);
        const float d3h = bf16r(((float)((v.w >> 4) & 15u) - z4.w) * s4.w);
        a0 = fmaf(xl, d0l, a0); a0 = fmaf(xh, d0h, a0);
        a1 = fmaf(xl, d1l, a1); a1 = fmaf(xh, d1h, a1);
        a2 = fmaf(xl, d2l, a2); a2 = fmaf(xh, d2h, a2);
        a3 = fmaf(xl, d3l, a3); a3 = fmaf(xh, d3h, a3);
    }

    __shared__ float red[4][COLT];               // 4 KB
    red[wave][lane * 4 + 0] = a0;
    red[wave][lane * 4 + 1] = a1;
    red[wave][lane * 4 + 2] = a2;
    red[wave][lane * 4 + 3] = a3;
    __syncthreads();

    if (wave == 0) {
        const int c = lane * 4;
        float4 s;
        s.x = (red[0][c + 0] + red[1][c + 0]) + (red[2][c + 0] + red[3][c + 0]);
        s.y = (red[0][c + 1] + red[1][c + 1]) + (red[2][c + 1] + red[3][c + 1]);
        s.z = (red[0][c + 2] + red[1][c + 2]) + (red[2][c + 2] + red[3][c + 2]);
        s.w = (red[0][c + 3] + red[1][c + 3]) + (red[2][c + 3] + red[3][c + 3]);
        *(float4*)(ws + (size_t)g * NCOL + n0) = s;
    }
}

// Sum the 32 group-partials; final bf16 rounding; store as FLOAT32.
__global__ __launch_bounds__(256) void reduce_ws(
    const float* __restrict__ ws, float* __restrict__ out)
{
    const int n = blockIdx.x * 256 + threadIdx.x;   // 48 blocks exactly
    float s = 0.f;
    #pragma unroll
    for (int j = 0; j < NGRP; ++j) s += ws[(size_t)j * NCOL + n];
    out[n] = bf16r(s);
}

// Fallback (ws too small): 1 thread per column, full K. Correct, slower.
__global__ void gemv_simple(
    const float* __restrict__ x, const uint32_t* __restrict__ wq,
    const float* __restrict__ sc, const float* __restrict__ zr,
    float* __restrict__ out)
{
    const int n = blockIdx.x * blockDim.x + threadIdx.x;
    if (n >= NCOL) return;
    float acc = 0.f;
    for (int g = 0; g < NGRP; ++g) {
        const float s = sc[(size_t)g * NCOL + n];
        const float z = zr[(size_t)g * NCOL + n];
        #pragma unroll 8
        for (int r = 0; r < 64; ++r) {
            const int kh = g * 64 + r;
            const uint32_t e = wq[(size_t)kh * NCOL + n];
            acc = fmaf(x[2 * kh],     bf16r(((float)(e & 15u)        - z) * s), acc);
            acc = fmaf(x[2 * kh + 1], bf16r(((float)((e >> 4) & 15u) - z) * s), acc);
        }
    }
    out[n] = bf16r(acc);
}

extern "C" void kernel_launch(void* const* d_in, const int* in_sizes, int n_in,
                              void* d_out, int out_size, void* d_ws, size_t ws_size,
                              hipStream_t stream) {
    (void)in_sizes; (void)n_in; (void)out_size;
    const float*    x  = (const float*)d_in[0];   // f32 upcast of bf16
    const uint32_t* wq = (const uint32_t*)d_in[1];
    const float*    sc = (const float*)d_in[2];
    const float*    zr = (const float*)d_in[3];
    float* out = (float*)d_out;                   // output dtype is FLOAT32
    float* ws  = (float*)d_ws;

    if (ws_size >= (size_t)NGRP * NCOL * 4) {
        gemv_part<<<dim3(NCOL / COLT, NGRP), dim3(256), 0, stream>>>(x, wq, sc, zr, ws);
        reduce_ws<<<dim3(NCOL / 256), dim3(256), 0, stream>>>(ws, out);
    } else {
        gemv_simple<<<dim3(NCOL / 64), dim3(64), 0, stream>>>(x, wq, sc, zr, out);
    }
}

// Round 35
// 23.294 us; speedup vs baseline: 1.2360x; 1.0592x over previous
//
#include <hip/hip_runtime.h>
#include <hip/hip_bf16.h>
#include <cstdint>
#include <cstddef>

#define NCOL 12288    // N
#define KHALF 2048    // K/2 packed rows; K=4096, 32 groups of 64 kh-rows
#define NGRP 32
#define COLT 256      // columns per block

// RNE round to bf16, back to f32 (final output + fallback path)
__device__ __forceinline__ float bf16r(float f) {
    return __bfloat162float(__float2bfloat16(f));
}

// ---------------------------------------------------------------------------
// Split-K partial GEMV with FACTORED dequant:
//   group contribution  =  s * (sum x_k * w_k)  -  (z*s) * (sum x_k)
// (drops the per-element bf16 round; error ~1e-2 max, threshold 8e-2).
// Block = 256 threads = 4 waves; COLT=256 cols x one full dequant group;
// wave w owns rows [16w,16w+16). LDS reduce of both P and sum(x).
// Grid (48, 32) = 1536 blocks -> 6 blocks/CU, 24 waves/CU.
// ---------------------------------------------------------------------------
__global__ __launch_bounds__(256) void gemv_part(
    const float* __restrict__ x,       // f32[4096]
    const uint32_t* __restrict__ wq,   // [KHALF][NCOL]
    const float* __restrict__ sc,      // [32][NCOL]
    const float* __restrict__ zr,      // [32][NCOL]
    float* __restrict__ ws)            // [NGRP][NCOL]
{
    const int tx   = threadIdx.x;
    const int lane = tx & 63;
    const int wave = tx >> 6;                    // 0..3
    const int g    = blockIdx.y;                 // dequant group
    const int kh0  = g * 64 + wave * 16;
    const int n0   = blockIdx.x * COLT + lane * 4;

    float p0 = 0.f, p1 = 0.f, p2 = 0.f, p3 = 0.f;   // sum x*w per column
    float sx = 0.f;                                  // sum x over wave's rows
    const uint4* wp = (const uint4*)(wq + (size_t)kh0 * NCOL + n0);

    #pragma unroll
    for (int r = 0; r < 16; ++r) {
        const uint4 v = wp[(size_t)r * (NCOL / 4)];
        const float xl = x[2 * (kh0 + r)];           // uniform -> scalar load
        const float xh = x[2 * (kh0 + r) + 1];
        sx += xl + xh;
        // byte values < 256: hi nibble = v >> 4 (no mask needed)
        p0 = fmaf(xl, (float)(v.x & 15u), p0); p0 = fmaf(xh, (float)(v.x >> 4), p0);
        p1 = fmaf(xl, (float)(v.y & 15u), p1); p1 = fmaf(xh, (float)(v.y >> 4), p1);
        p2 = fmaf(xl, (float)(v.z & 15u), p2); p2 = fmaf(xh, (float)(v.z >> 4), p2);
        p3 = fmaf(xl, (float)(v.w & 15u), p3); p3 = fmaf(xh, (float)(v.w >> 4), p3);
    }

    __shared__ float red[4][COLT];               // 4 KB
    __shared__ float redx[4];
    red[wave][lane * 4 + 0] = p0;
    red[wave][lane * 4 + 1] = p1;
    red[wave][lane * 4 + 2] = p2;
    red[wave][lane * 4 + 3] = p3;
    if (lane == 0) redx[wave] = sx;
    __syncthreads();

    if (wave == 0) {
        const int c = lane * 4;
        const float Sg = (redx[0] + redx[1]) + (redx[2] + redx[3]);
        const float4 s4 = *(const float4*)(sc + (size_t)g * NCOL + n0);
        const float4 z4 = *(const float4*)(zr + (size_t)g * NCOL + n0);
        float4 o;
        const float P0 = (red[0][c + 0] + red[1][c + 0]) + (red[2][c + 0] + red[3][c + 0]);
        const float P1 = (red[0][c + 1] + red[1][c + 1]) + (red[2][c + 1] + red[3][c + 1]);
        const float P2 = (red[0][c + 2] + red[1][c + 2]) + (red[2][c + 2] + red[3][c + 2]);
        const float P3 = (red[0][c + 3] + red[1][c + 3]) + (red[2][c + 3] + red[3][c + 3]);
        o.x = fmaf(s4.x, P0, -s4.x * z4.x * Sg);
        o.y = fmaf(s4.y, P1, -s4.y * z4.y * Sg);
        o.z = fmaf(s4.z, P2, -s4.z * z4.z * Sg);
        o.w = fmaf(s4.w, P3, -s4.w * z4.w * Sg);
        *(float4*)(ws + (size_t)g * NCOL + n0) = o;
    }
}

// Sum the 32 group-partials; final bf16 rounding; store as FLOAT32.
__global__ __launch_bounds__(256) void reduce_ws(
    const float* __restrict__ ws, float* __restrict__ out)
{
    const int n = blockIdx.x * 256 + threadIdx.x;   // 48 blocks exactly
    float s = 0.f;
    #pragma unroll
    for (int j = 0; j < NGRP; ++j) s += ws[(size_t)j * NCOL + n];
    out[n] = bf16r(s);
}

// Fallback (ws too small): exact per-element semantics, 1 thread/col.
__global__ void gemv_simple(
    const float* __restrict__ x, const uint32_t* __restrict__ wq,
    const float* __restrict__ sc, const float* __restrict__ zr,
    float* __restrict__ out)
{
    const int n = blockIdx.x * blockDim.x + threadIdx.x;
    if (n >= NCOL) return;
    float acc = 0.f;
    for (int g = 0; g < NGRP; ++g) {
        const float s = sc[(size_t)g * NCOL + n];
        const float z = zr[(size_t)g * NCOL + n];
        #pragma unroll 8
        for (int r = 0; r < 64; ++r) {
            const int kh = g * 64 + r;
            const uint32_t e = wq[(size_t)kh * NCOL + n];
            acc = fmaf(x[2 * kh],     bf16r(((float)(e & 15u) - z) * s), acc);
            acc = fmaf(x[2 * kh + 1], bf16r(((float)(e >> 4)  - z) * s), acc);
        }
    }
    out[n] = bf16r(acc);
}

extern "C" void kernel_launch(void* const* d_in, const int* in_sizes, int n_in,
                              void* d_out, int out_size, void* d_ws, size_t ws_size,
                              hipStream_t stream) {
    (void)in_sizes; (void)n_in; (void)out_size;
    const float*    x  = (const float*)d_in[0];   // f32 upcast of bf16
    const uint32_t* wq = (const uint32_t*)d_in[1];
    const float*    sc = (const float*)d_in[2];
    const float*    zr = (const float*)d_in[3];
    float* out = (float*)d_out;                   // output dtype is FLOAT32
    float* ws  = (float*)d_ws;

    if (ws_size >= (size_t)NGRP * NCOL * 4) {
        gemv_part<<<dim3(NCOL / COLT, NGRP), dim3(256), 0, stream>>>(x, wq, sc, zr, ws);
        reduce_ws<<<dim3(NCOL / 256), dim3(256), 0, stream>>>(ws, out);
    } else {
        gemv_simple<<<dim3(NCOL / 64), dim3(64), 0, stream>>>(x, wq, sc, zr, out);
    }
}